// Round 6
// baseline (1439.711 us; speedup 1.0000x reference)
//
#include <hip/hip_runtime.h>
#include <stdint.h>

#define DIM 2048
#define SEQ 2048
#define NHEADS 16
#define HDIM 128
#define BSZ 2
#define ROWS (BSZ*SEQ)   // 4096

typedef uint16_t u16;
typedef __attribute__((ext_vector_type(8))) short bf16x8;
typedef __attribute__((ext_vector_type(4))) short bf16x4;
typedef __attribute__((ext_vector_type(4))) float fx4;
typedef __attribute__((ext_vector_type(4))) uint16_t u16x4;

typedef const __attribute__((address_space(1))) uint32_t* gp_t;
typedef __attribute__((address_space(3))) uint32_t* lp_t;
#define GLL16(g, l) __builtin_amdgcn_global_load_lds((gp_t)(g), (lp_t)(l), 16, 0, 0)

__device__ inline float exp2_fast(float x) { return __builtin_amdgcn_exp2f(x); }  // v_exp_f32: 2^x

__device__ inline u16 f2bf(float f) {
  union { float f; uint32_t u; } v; v.f = f;
  uint32_t u = v.u;
  u += 0x7FFFu + ((u >> 16) & 1u);   // RNE
  return (u16)(u >> 16);
}
__device__ inline float bf2f(u16 h) {
  union { uint32_t u; float f; } v; v.u = ((uint32_t)h) << 16;
  return v.f;
}

// ---------------------------------------------------------------- fused convert fp32 -> bf16
__global__ __launch_bounds__(256) void cvt5_kernel(const float* __restrict__ sx,
    const float* __restrict__ s1, const float* __restrict__ s2,
    const float* __restrict__ s3, const float* __restrict__ s4,
    u16* __restrict__ dst) {
  const int XC = (ROWS * DIM) / 4;
  const int WC = (DIM * DIM) / 4;          // 2^20
  int i = blockIdx.x * 256 + threadIdx.x;
  const float* src;
  int off;
  if (i < XC) { src = sx; off = i; }
  else {
    int t = i - XC;
    int w = t >> 20;
    off = t & (WC - 1);
    src = (w == 0) ? s1 : (w == 1) ? s2 : (w == 2) ? s3 : s4;
  }
  fx4 f = *(const fx4*)(src + (size_t)off * 4);
  u16x4 o;
  o[0] = f2bf(f[0]); o[1] = f2bf(f[1]); o[2] = f2bf(f[2]); o[3] = f2bf(f[3]);
  *(u16x4*)(dst + (size_t)i * 4) = o;
}

// ---------------------------------------------------------------- GEMM core (m97 pattern)
__device__ inline void gemm128_core(const u16* __restrict__ A, const u16* __restrict__ B,
                                    u16 (&As)[128][32], u16 (&Bs)[128][32],
                                    fx4 (&acc)[4][4], int M0, int N0) {
  const int tid  = threadIdx.x;
  const int lane = tid & 63;
  const int wave = tid >> 6;
  const int wm = (wave >> 1) * 64;
  const int wn = (wave & 1) * 64;
  const int l16 = lane & 15;
  const int q8  = (lane >> 4) * 8;
#pragma unroll
  for (int tm = 0; tm < 4; ++tm)
#pragma unroll
    for (int tn = 0; tn < 4; ++tn) acc[tm][tn] = fx4{0.f, 0.f, 0.f, 0.f};

  const int wrow = wave * 32;
  const size_t laneA = (size_t)(M0 + wrow + (lane >> 2)) * DIM + (lane & 3) * 8;
  const size_t laneB = (size_t)(N0 + wrow + (lane >> 2)) * DIM + (lane & 3) * 8;

  for (int k0 = 0; k0 < DIM; k0 += 32) {
    __syncthreads();
    GLL16(A + laneA + k0,            &As[wrow][0]);
    GLL16(A + laneA + 16 * DIM + k0, &As[wrow + 16][0]);
    GLL16(B + laneB + k0,            &Bs[wrow][0]);
    GLL16(B + laneB + 16 * DIM + k0, &Bs[wrow + 16][0]);
    __syncthreads();
    bf16x8 af[4], bfr[4];
#pragma unroll
    for (int t = 0; t < 4; ++t) {
      af[t]  = *(const bf16x8*)&As[wm + t * 16 + l16][q8];
      bfr[t] = *(const bf16x8*)&Bs[wn + t * 16 + l16][q8];
    }
#pragma unroll
    for (int tm = 0; tm < 4; ++tm)
#pragma unroll
      for (int tn = 0; tn < 4; ++tn)
        acc[tm][tn] = __builtin_amdgcn_mfma_f32_16x16x32_bf16(af[tm], bfr[tn], acc[tm][tn], 0, 0, 0);
  }
}

__global__ __launch_bounds__(256) void gemm_qkv(const u16* __restrict__ A,
    const u16* __restrict__ B0, const u16* __restrict__ B1, const u16* __restrict__ B2,
    u16* __restrict__ C0, u16* __restrict__ C1, u16* __restrict__ C2) {
  __shared__ __align__(16) u16 As[128][32];
  __shared__ __align__(16) u16 Bs[128][32];
  const u16* B = (blockIdx.z == 0) ? B0 : (blockIdx.z == 1) ? B1 : B2;
  u16* C       = (blockIdx.z == 0) ? C0 : (blockIdx.z == 1) ? C1 : C2;
  const int M0 = blockIdx.y * 128, N0 = blockIdx.x * 128;
  fx4 acc[4][4];
  gemm128_core(A, B, As, Bs, acc, M0, N0);
  const int lane = threadIdx.x & 63, wave = threadIdx.x >> 6;
  const int wm = (wave >> 1) * 64, wn = (wave & 1) * 64;
  const int l16 = lane & 15, quad = lane >> 4;
#pragma unroll
  for (int tm = 0; tm < 4; ++tm)
#pragma unroll
    for (int tn = 0; tn < 4; ++tn)
#pragma unroll
      for (int r = 0; r < 4; ++r) {
        size_t row = (size_t)(M0 + wm + tm * 16 + quad * 4 + r);
        size_t col = (size_t)(N0 + wn + tn * 16 + l16);
        C[row * DIM + col] = f2bf(acc[tm][tn][r]);
      }
}

__global__ __launch_bounds__(256) void gemm_out(const u16* __restrict__ A,
                                                const u16* __restrict__ B,
                                                float* __restrict__ C) {
  __shared__ __align__(16) u16 As[128][32];
  __shared__ __align__(16) u16 Bs[128][32];
  const int M0 = blockIdx.y * 128, N0 = blockIdx.x * 128;
  fx4 acc[4][4];
  gemm128_core(A, B, As, Bs, acc, M0, N0);
  const int lane = threadIdx.x & 63, wave = threadIdx.x >> 6;
  const int wm = (wave >> 1) * 64, wn = (wave & 1) * 64;
  const int l16 = lane & 15, quad = lane >> 4;
#pragma unroll
  for (int tm = 0; tm < 4; ++tm)
#pragma unroll
    for (int tn = 0; tn < 4; ++tn)
#pragma unroll
      for (int r = 0; r < 4; ++r) {
        size_t row = (size_t)(M0 + wm + tm * 16 + quad * 4 + r);
        size_t col = (size_t)(N0 + wn + tn * 16 + l16);
        C[row * DIM + col] = acc[tm][tn][r];
      }
}

// ---------------------------------------------------------------- fused prep: RoPE(Q), RoPE(K), V-transpose
// blocks [0,4096): rope Q; [4096,8192): rope K; [8192,9216): vtrans.
__global__ __launch_bounds__(256) void prep_kernel(u16* __restrict__ q, u16* __restrict__ k,
                                                   const u16* __restrict__ v, u16* __restrict__ vtg,
                                                   const float* __restrict__ fcos,
                                                   const float* __restrict__ fsin) {
  const int bx = blockIdx.x;
  if (bx < 8192) {
    u16* ptr = (bx < 4096) ? q : k;
    int gid = (bx & 4095) * 256 + threadIdx.x;   // 0..2^20-1, 8 bf16 (4 rope pairs) each
    int row = gid >> 8;                          // 0..4095
    int ch  = gid & 255;                         // 8-elem chunk within the 2048 row
    int s   = row & (SEQ - 1);
    int p0  = (ch & 15) * 4;                     // first pair index within head
    size_t base = (size_t)row * DIM + ch * 8;
    bf16x8 t = *(const bf16x8*)(ptr + base);
    fx4 c  = *(const fx4*)(fcos + s * 64 + p0);
    fx4 sn = *(const fx4*)(fsin + s * 64 + p0);
    bf16x8 o;
#pragma unroll
    for (int j = 0; j < 4; ++j) {
      float a = bf2f((u16)t[2 * j]), b = bf2f((u16)t[2 * j + 1]);
      o[2 * j]     = (short)f2bf(a * c[j] - b * sn[j]);
      o[2 * j + 1] = (short)f2bf(a * sn[j] + b * c[j]);
    }
    *(bf16x8*)(ptr + base) = o;
  } else {
    __shared__ __align__(16) u16 T[128][72];
    const int tid = threadIdx.x;
    const int bx2 = bx - 8192;
    const int s0 = (bx2 & 31) * 64;
    const int bh = bx2 >> 5;
    const int b = bh >> 4, h = bh & 15;
    const size_t vb = ((size_t)b * SEQ + s0) * DIM + h * HDIM;
#pragma unroll
    for (int i = 0; i < 4; ++i) {
      int c = i * 256 + tid;
      int s = c >> 4;
      int d0 = (c & 15) * 8;
      bf16x8 x = *(const bf16x8*)(v + vb + (size_t)s * DIM + d0);
#pragma unroll
      for (int j = 0; j < 8; ++j) T[d0 + j][s] = (u16)x[j];
    }
    __syncthreads();
    const size_t ob = ((size_t)bh * HDIM) * SEQ + s0;
#pragma unroll
    for (int i = 0; i < 4; ++i) {
      int c = i * 256 + tid;
      int d = c >> 3;
      int s8 = (c & 7) * 8;
      *(bf16x8*)(vtg + ob + (size_t)d * SEQ + s8) = *(const bf16x8*)&T[d][s8];
    }
  }
}

// ---------------------------------------------------------------- flash attention, S^T form
// S^T = K·Q^T so P^T (C-layout) is directly the B-operand of mfma_16x16x16bf16_1k:
// PV needs no LDS round-trip. Two-stage register prefetch covers HBM latency.
// Softmax in exp2 domain (scale = 1/sqrt(128) * log2e folded into S).
struct SMemS { u16 Ks[64][136]; u16 Vt[128][72]; };
union SMemU { SMemS s; u16 Ot[4][32][136]; };

__global__ __launch_bounds__(256, 2) void attn_kernel(const u16* __restrict__ qm,
                                                      const u16* __restrict__ km,
                                                      const u16* __restrict__ vtg,
                                                      u16* __restrict__ ao) {
  __shared__ __align__(16) SMemU sm;
  const int tid = threadIdx.x;
  const int lane = tid & 63, wave = tid >> 6;
  const int l16 = lane & 15, quad = lane >> 4;
  const int idx = blockIdx.x;
  const int bh = idx & 31;
  const int j = idx >> 5;
  const int qt = (j < 8) ? (15 - j) : (j - 8);   // complementary pairing
  const int b = bh >> 4, h = bh & 15;
  const int q0 = qt * 128;
  const size_t brow = (size_t)b * SEQ;
  const int hc = h * HDIM;
  const size_t vbase = (size_t)bh * HDIM * SEQ;
  const int nkt = 2 * qt + 2;                    // >= 2 always

  bf16x8 aq[2][4];
#pragma unroll
  for (int nt = 0; nt < 2; ++nt) {
    size_t qbase = (brow + q0 + wave * 32 + nt * 16 + l16) * DIM + hc;
#pragma unroll
    for (int dc = 0; dc < 4; ++dc)
      aq[nt][dc] = *(const bf16x8*)(qm + qbase + dc * 32 + quad * 8);
  }
  fx4 o[2][8];
#pragma unroll
  for (int nt = 0; nt < 2; ++nt)
#pragma unroll
    for (int dt = 0; dt < 8; ++dt) o[nt][dt] = fx4{0.f, 0.f, 0.f, 0.f};
  float mr[2] = {-3e38f, -3e38f}, lr[2] = {0.f, 0.f};

  // two-stage register prefetch
  const int kr = tid >> 4, kc = (tid & 15) * 8;        // K tile coords per chunk base
  const int vr = tid >> 3, vc = (tid & 7) * 8;         // V^T tile coords
  bf16x8 kreg[2][4], vreg[2][4];
#pragma unroll
  for (int st = 0; st < 2; ++st) {
    const int kv = st * 64;
#pragma unroll
    for (int i = 0; i < 4; ++i) {
      int rr = kr + i * 16, vv = vr + i * 32;
      kreg[st][i] = *(const bf16x8*)(km + (brow + kv + rr) * DIM + hc + kc);
      vreg[st][i] = *(const bf16x8*)(vtg + vbase + (size_t)vv * SEQ + kv + vc);
    }
  }

  for (int kt = 0; kt < nkt; ++kt) {
    const int cur = kt & 1;
    __syncthreads();
#pragma unroll
    for (int i = 0; i < 4; ++i) {
      *(bf16x8*)&sm.s.Ks[kr + i * 16][kc] = kreg[cur][i];
      *(bf16x8*)&sm.s.Vt[vr + i * 32][vc] = vreg[cur][i];
    }
    __syncthreads();
    if (kt + 2 < nkt) {
      const int kv2 = (kt + 2) * 64;
#pragma unroll
      for (int i = 0; i < 4; ++i) {
        int rr = kr + i * 16, vv = vr + i * 32;
        kreg[cur][i] = *(const bf16x8*)(km + (brow + kv2 + rr) * DIM + hc + kc);
        vreg[cur][i] = *(const bf16x8*)(vtg + vbase + (size_t)vv * SEQ + kv2 + vc);
      }
    }
    // S^T = K Q^T (exp2-domain scale folded in)
    fx4 s[2][4];
#pragma unroll
    for (int tm = 0; tm < 4; ++tm) {
      fx4 a0 = fx4{0.f, 0.f, 0.f, 0.f}, a1 = fx4{0.f, 0.f, 0.f, 0.f};
#pragma unroll
      for (int dc = 0; dc < 4; ++dc) {
        bf16x8 kf = *(const bf16x8*)&sm.s.Ks[tm * 16 + l16][dc * 32 + quad * 8];
        a0 = __builtin_amdgcn_mfma_f32_16x16x32_bf16(kf, aq[0][dc], a0, 0, 0, 0);
        a1 = __builtin_amdgcn_mfma_f32_16x16x32_bf16(kf, aq[1][dc], a1, 0, 0, 0);
      }
      s[0][tm] = a0 * 0.1275174313f;   // 1/sqrt(128) * log2(e)
      s[1][tm] = a1 * 0.1275174313f;
    }
    if (kt >= nkt - 2) {
      const int kv0 = kt * 64;
#pragma unroll
      for (int nt = 0; nt < 2; ++nt) {
        int qpos = q0 + wave * 32 + nt * 16 + l16;
#pragma unroll
        for (int tm = 0; tm < 4; ++tm)
#pragma unroll
          for (int r = 0; r < 4; ++r)
            if (kv0 + tm * 16 + quad * 4 + r > qpos) s[nt][tm][r] = -1e30f;
      }
    }
    // online softmax (exp2 domain) over kv; q = l16 per tile
    float alpha[2];
    bf16x4 pf[2][4];
#pragma unroll
    for (int nt = 0; nt < 2; ++nt) {
      float t = -3e38f;
#pragma unroll
      for (int tm = 0; tm < 4; ++tm)
        t = fmaxf(t, fmaxf(fmaxf(s[nt][tm][0], s[nt][tm][1]),
                           fmaxf(s[nt][tm][2], s[nt][tm][3])));
      t = fmaxf(t, __shfl_xor(t, 16));
      t = fmaxf(t, __shfl_xor(t, 32));
      float mnew = fmaxf(mr[nt], t);
      alpha[nt] = exp2_fast(mr[nt] - mnew);
      float sum = 0.f;
#pragma unroll
      for (int tm = 0; tm < 4; ++tm) {
        fx4 p;
#pragma unroll
        for (int r = 0; r < 4; ++r) {
          p[r] = exp2_fast(s[nt][tm][r] - mnew);
          sum += p[r];
        }
        bf16x4 pb;
        pb[0] = (short)f2bf(p[0]); pb[1] = (short)f2bf(p[1]);
        pb[2] = (short)f2bf(p[2]); pb[3] = (short)f2bf(p[3]);
        pf[nt][tm] = pb;
      }
      sum += __shfl_xor(sum, 16);
      sum += __shfl_xor(sum, 32);
      lr[nt] = lr[nt] * alpha[nt] + sum;
      mr[nt] = mnew;
#pragma unroll
      for (int dt = 0; dt < 8; ++dt) o[nt][dt] *= alpha[nt];
    }
    // O^T += V^T P^T (B-operand straight from registers)
#pragma unroll
    for (int tm = 0; tm < 4; ++tm) {
#pragma unroll
      for (int dt = 0; dt < 8; ++dt) {
        bf16x4 vf = *(const bf16x4*)&sm.s.Vt[dt * 16 + l16][tm * 16 + quad * 4];
        o[0][dt] = __builtin_amdgcn_mfma_f32_16x16x16bf16_1k(vf, pf[0][tm], o[0][dt], 0, 0, 0);
        o[1][dt] = __builtin_amdgcn_mfma_f32_16x16x16bf16_1k(vf, pf[1][tm], o[1][dt], 0, 0, 0);
      }
    }
  }
  // epilogue: O^T -> LDS transpose -> coalesced global
  __syncthreads();
#pragma unroll
  for (int nt = 0; nt < 2; ++nt) {
    float inv = 1.f / lr[nt];
#pragma unroll
    for (int dt = 0; dt < 8; ++dt) {
      fx4 v = o[nt][dt];
      u16x4 p;
      p[0] = f2bf(v[0] * inv); p[1] = f2bf(v[1] * inv);
      p[2] = f2bf(v[2] * inv); p[3] = f2bf(v[3] * inv);
      *(u16x4*)&sm.Ot[wave][nt * 16 + l16][dt * 16 + quad * 4] = p;
    }
  }
#pragma unroll
  for (int i = 0; i < 8; ++i) {
    int c = i * 64 + lane;
    int row = c >> 4;
    int ch = c & 15;
    bf16x8 t = *(const bf16x8*)&sm.Ot[wave][row][ch * 8];
    *(bf16x8*)(ao + (brow + q0 + wave * 32 + row) * DIM + hc + ch * 8) = t;
  }
}

// ---------------------------------------------------------------- launch
extern "C" void kernel_launch(void* const* d_in, const int* in_sizes, int n_in,
                              void* d_out, int out_size, void* d_ws, size_t ws_size,
                              hipStream_t stream) {
  const float* x    = (const float*)d_in[0];
  const float* fcos = (const float*)d_in[2];
  const float* fsin = (const float*)d_in[3];
  const float* wq   = (const float*)d_in[5];
  const float* wk   = (const float*)d_in[6];
  const float* wv   = (const float*)d_in[7];
  const float* wo   = (const float*)d_in[8];
  float* out = (float*)d_out;

  const size_t XN = (size_t)ROWS * DIM;
  const size_t WN = (size_t)DIM * DIM;
  u16* ws  = (u16*)d_ws;
  u16* xb  = ws;
  u16* wqb = xb + XN;
  u16* wkb = wqb + WN;
  u16* wvb = wkb + WN;
  u16* wob = wvb + WN;
  u16* q   = wob + WN;
  u16* k   = q + XN;
  u16* v   = k + XN;
  u16* ao  = v + XN;
  u16* vtg = xb;   // alias: x-bf16 dead after gemm_qkv

  const int total_chunks = (int)((XN + 4 * WN) / 4);
  cvt5_kernel<<<total_chunks / 256, 256, 0, stream>>>(x, wq, wk, wv, wo, ws);

  gemm_qkv<<<dim3(DIM / 128, ROWS / 128, 3), 256, 0, stream>>>(xb, wqb, wkb, wvb, q, k, v);

  prep_kernel<<<dim3(9216), 256, 0, stream>>>(q, k, v, vtg, fcos, fsin);

  attn_kernel<<<dim3(512), 256, 0, stream>>>(q, k, vtg, ao);

  gemm_out<<<dim3(DIM / 128, ROWS / 128), 256, 0, stream>>>(ao, wob, out);
}